// Round 5
// baseline (248.898 us; speedup 1.0000x reference)
//
#include <hip/hip_runtime.h>

// ViT cls-token-only forward. B=16, C=8, D=511, H=W=16, DIM=2048, SEQ=512,
// NH=16, HD=128.
// q = (cls+pos0) @ Wq + bq is batch-independent (one 2048-vector).
// scores[b,h,j] = tok[b,j] . r[h],  r[h] = Wk[:,h*128:+128] @ q[h]  (scaled)
// u[b,h] = sum_j p[b,h,j] * tok[b,j];  ao[b,h] = u[b,h] @ Wv slice + bv
// out[b] = ao[b] @ proj_w + proj_b
//
// R5: occupancy + traffic pass.
//  - k3: K-split x4 (2048 waves = 2/SIMD, was 1) + cheap truncation hi/lo
//    split (hi=top16, lo=f-hi exact then truncate; rel err ~2^-16).
//  - k5: atomicAdd straight into one 2 MB u buffer — kills the 8x partial
//    write + k6 q-sum re-read (~67 MB less traffic).
//  - k2: computes full 128-e dot per thread (no atomic), writes fp32 r AND
//    bf16 hi/lo in one pass — k2c launch eliminated. 256 blocks x 128 thr.
//  - k6/k7: reduction chunks 64->32, 512 blocks = 2 blocks/CU.

#define BB   16
#define CC   8
#define DD   511
#define DIM  2048
#define SEQ  512
#define NH   16
#define HD   128
#define W3   6144
#define SCALE 0.08838834764831845f

// workspace layout (float offsets)
#define Q_OFF   0            // 2048    (atomic -> memset)
#define AO_OFF  2048         // 32768   (atomic -> memset)
#define R_OFF   34816        // 32768   fp32 r (plain write by k2)
#define G_OFF   67584        // 16      gamma
#define SC_OFF  67600        // 131072  scores (atomic -> memset), softmax in place
#define U_OFF   198672       // 524288  u accumulators (atomic -> memset)
#define RB_OFF  722960       // 32768 float slots = 65536 shorts: r bf16 hi/lo
// total = 755,728 floats ~= 3.0 MB; memset covers [0, RB_OFF)

typedef __attribute__((ext_vector_type(8))) short short8;
typedef __attribute__((ext_vector_type(4))) float floatx4;

static __device__ inline short bf_hi(float f) {
  return (short)(__float_as_uint(f) >> 16);          // truncate to bf16
}
static __device__ inline float bf_hif(float f) {
  return __uint_as_float(__float_as_uint(f) & 0xffff0000u);
}

// K1: q[n] = sum_d (cls[d]+pos[d]) * Wq[d][n] + bq[n]   grid (8 ntile, 64 dchunk)
__global__ __launch_bounds__(256) void k1_q(
    const float* __restrict__ pos, const float* __restrict__ cls,
    const float* __restrict__ qkv_w, const float* __restrict__ qkv_b,
    float* __restrict__ ws) {
  int n  = blockIdx.x * 256 + threadIdx.x;
  int d0 = blockIdx.y * 32;
  float acc = (blockIdx.y == 0) ? qkv_b[n] : 0.f;
#pragma unroll 8
  for (int d = d0; d < d0 + 32; ++d) {
    float t0 = cls[d] + pos[d];           // uniform -> scalar load
    acc += t0 * qkv_w[(size_t)d * W3 + n];
  }
  atomicAdd(&ws[Q_OFF + n], acc);
}

// K2: r[h][d] = SCALE * (Wk[d, h-slice] . q[h-slice]); writes fp32 r and
// bf16 hi/lo in one pass. grid (16 dtile, 16 h), block 128.
__global__ __launch_bounds__(128) void k2_r(
    const float* __restrict__ qkv_w, float* __restrict__ ws) {
  __shared__ float qs[HD];
  int h = blockIdx.y;
  int d = blockIdx.x * 128 + threadIdx.x;
  if (threadIdx.x < HD) qs[threadIdx.x] = ws[Q_OFF + h * HD + threadIdx.x];
  __syncthreads();
  const float4* w4 = reinterpret_cast<const float4*>(
      qkv_w + (size_t)d * W3 + DIM + h * HD);
  float acc = 0.f;
#pragma unroll 8
  for (int e4 = 0; e4 < 32; ++e4) {
    float4 w = w4[e4];
    acc += qs[e4*4+0]*w.x + qs[e4*4+1]*w.y + qs[e4*4+2]*w.z + qs[e4*4+3]*w.w;
  }
  float r = acc * SCALE;
  int i = h * DIM + d;
  ws[R_OFF + i] = r;
  short* rb = (short*)(ws + RB_OFF);
  short hi = bf_hi(r);
  rb[i] = hi;
  rb[NH * DIM + i] = bf_hi(r - bf_hif(r));
}

// K2b: gamma[h] = tok0 . r[h]  (j=0 score; k-bias dropped: softmax shift-invariant)
__global__ __launch_bounds__(256) void k2b_gamma(
    const float* __restrict__ pos, const float* __restrict__ cls,
    float* __restrict__ ws) {
  __shared__ float red[256];
  int h = blockIdx.x, t = threadIdx.x;
  float part = 0.f;
  for (int d = t; d < DIM; d += 256)
    part += (cls[d] + pos[d]) * ws[R_OFF + h * DIM + d];
  red[t] = part;
  __syncthreads();
  for (int s = 128; s > 0; s >>= 1) {
    if (t < s) red[t] += red[t + s];
    __syncthreads();
  }
  if (t == 0) ws[G_OFF + h] = red[0];
}

// K3: scores[b,h,j] for j>=1 via MFMA. Per-wave tile: 16 j x 16 h, K-quarter
// of 512. grid (32 jt, 16 b, 4 ks), block 64 (one wave, 2 waves/SIMD).
// 3-term hi/lo compensation: hi*hi + hi*lo + lo*hi.
__global__ __launch_bounds__(64) void k3_scores_mfma(
    const float* __restrict__ x, const float* __restrict__ pos,
    float* __restrict__ ws) {
  int jt = blockIdx.x, b = blockIdx.y, ks = blockIdx.z;
  int l  = threadIdx.x;          // 0..63
  int m  = l & 15;               // A-row (j) / B-row (h)
  int kg = l >> 4;               // k-quad
  int jrow = 1 + jt * 16 + m;    // 1..512
  int jc = jrow < SEQ ? jrow : (SEQ - 1);   // clamp; jrow==512 masked at store
  const size_t xrow = (size_t)b * CC * DD * 256 + (size_t)(jc - 1) * 256;
  const short* rh = (const short*)(ws + RB_OFF);
  const short* rl = rh + NH * DIM;
  floatx4 acc = {0.f, 0.f, 0.f, 0.f};
#pragma unroll 2
  for (int kk = ks * 16; kk < ks * 16 + 16; ++kk) {
    int d0 = kk * 32 + kg * 8;            // 8 consecutive d for this lane
    int c = d0 >> 8, doff = d0 & 255;
    const float4* xp = reinterpret_cast<const float4*>(
        x + xrow + (size_t)c * DD * 256 + doff);
    const float4* pp = reinterpret_cast<const float4*>(
        pos + (size_t)jc * DIM + d0);
    float4 xa = xp[0], xb = xp[1];
    float4 pa = pp[0], pb = pp[1];
    float f[8] = {xa.x + pa.x, xa.y + pa.y, xa.z + pa.z, xa.w + pa.w,
                  xb.x + pb.x, xb.y + pb.y, xb.z + pb.z, xb.w + pb.w};
    short8 ahi, alo;
#pragma unroll
    for (int i = 0; i < 8; ++i) {
      ahi[i] = bf_hi(f[i]);
      alo[i] = bf_hi(f[i] - bf_hif(f[i]));   // f-hi exact, then truncate
    }
    short8 bhi = *reinterpret_cast<const short8*>(rh + m * DIM + d0);
    short8 blo = *reinterpret_cast<const short8*>(rl + m * DIM + d0);
    acc = __builtin_amdgcn_mfma_f32_16x16x32_bf16(ahi, bhi, acc, 0, 0, 0);
    acc = __builtin_amdgcn_mfma_f32_16x16x32_bf16(ahi, blo, acc, 0, 0, 0);
    acc = __builtin_amdgcn_mfma_f32_16x16x32_bf16(alo, bhi, acc, 0, 0, 0);
  }
  // C layout: col(h) = l&15, row(j) = (l>>4)*4 + reg  [m89-verified]
  int h = m;
#pragma unroll
  for (int reg = 0; reg < 4; ++reg) {
    int row = kg * 4 + reg;
    int j = 1 + jt * 16 + row;
    if (j < SEQ)
      atomicAdd(&ws[SC_OFF + (size_t)(b * NH + h) * SEQ + j], acc[reg]);
  }
}

// K4: softmax per (b,h) row of 512, in place. j=0 score comes from gamma[h].
__global__ __launch_bounds__(256) void k4_softmax(float* __restrict__ ws) {
  int h = blockIdx.x, b = blockIdx.y, t = threadIdx.x;
  float* sc = ws + SC_OFF + (size_t)(b * NH + h) * SEQ;
  __shared__ float red[256];
  float s0 = (t == 0) ? ws[G_OFF + h] : sc[t];
  float s1 = sc[t + 256];
  red[t] = fmaxf(s0, s1);
  __syncthreads();
  for (int s = 128; s > 0; s >>= 1) { if (t < s) red[t] = fmaxf(red[t], red[t + s]); __syncthreads(); }
  float m = red[0];
  __syncthreads();
  float e0 = __expf(s0 - m), e1 = __expf(s1 - m);
  red[t] = e0 + e1;
  __syncthreads();
  for (int s = 128; s > 0; s >>= 1) { if (t < s) red[t] += red[t + s]; __syncthreads(); }
  float inv = 1.f / red[0];
  sc[t] = e0 * inv;
  sc[t + 256] = e1 * inv;
}

// K5: u[b][h][d] += sum over 64-j chunk of p[b,h,j]*tok[b,j][d], via atomics
// (replaces 8x partial buffers + k6 q-sum). p staged in LDS, 4-j chunks,
// unroll 2. grid (8 c, 8 qc, 16 b).
__global__ __launch_bounds__(256) void k5_u(
    const float* __restrict__ x, const float* __restrict__ pos,
    const float* __restrict__ cls, float* __restrict__ ws) {
  int c = blockIdx.x, qc = blockIdx.y, b = blockIdx.z, t = threadIdx.x;
  int d = c * 256 + t;
  __shared__ float pl[NH][64];
  __shared__ float pl0[NH];
  const float* pp = ws + SC_OFF + (size_t)b * NH * SEQ;
  int j0 = 1 + qc * 64;
  for (int i = t; i < NH * 64; i += 256) {
    int h = i >> 6, jj = i & 63;
    int j = j0 + jj;
    pl[h][jj] = (j < SEQ) ? pp[h * SEQ + j] : 0.f;
  }
  if (t < NH) pl0[t] = pp[t * SEQ];
  __syncthreads();
  float acc[NH];
  if (qc == 0) {
    float t0 = cls[d] + pos[d];
#pragma unroll
    for (int h = 0; h < NH; ++h) acc[h] = pl0[h] * t0;   // j=0 cls token
  } else {
#pragma unroll
    for (int h = 0; h < NH; ++h) acc[h] = 0.f;
  }
  const size_t xb = (size_t)b * CC * DD * 256 + (size_t)c * DD * 256 + t;
  const float* posc = pos + c * 256 + t;
#pragma unroll 2
  for (int jt = 0; jt < 64; jt += 4) {
    float xvv[4];
#pragma unroll
    for (int jj = 0; jj < 4; ++jj) {
      int j = j0 + jt + jj;
      xvv[jj] = (j < SEQ)
          ? x[xb + (size_t)(j - 1) * 256] + posc[(size_t)j * DIM]
          : 0.f;
    }
#pragma unroll
    for (int h = 0; h < NH; ++h) {
      float4 p4 = *reinterpret_cast<const float4*>(&pl[h][jt]);  // broadcast
      acc[h] += p4.x * xvv[0] + p4.y * xvv[1] + p4.z * xvv[2] + p4.w * xvv[3];
    }
  }
  float* u = ws + U_OFF + (size_t)(b * NH) * DIM + d;
#pragma unroll
  for (int h = 0; h < NH; ++h) atomicAdd(&u[(size_t)h * DIM], acc[h]);
}

// K6: ao[b][m] += sum over 32-d chunk of u[b][h][d]*Wv[d][4096+m] (+bv),
// m = h*128+e. ALL 16 batches per block -> Wv read once. grid (8 nt, 64 dc).
__global__ __launch_bounds__(256) void k6_ao(
    const float* __restrict__ qkv_w, const float* __restrict__ qkv_b,
    float* __restrict__ ws) {
  int nt = blockIdx.x, dc = blockIdx.y, t = threadIdx.x;
  int m = nt * 256 + t;
  int h0 = nt * 2;                        // 2 heads per 256-wide n tile
  int d0 = dc * 32;
  __shared__ float us[2][32][20];         // stride 20: 16B-aligned rows
  for (int i = t; i < 2 * 32 * BB; i += 256) {
    int dd = i & 31, b = (i >> 5) & 15, hh = i >> 9;
    us[hh][dd][b] = ws[U_OFF + (size_t)(b * NH + h0 + hh) * DIM + d0 + dd];
  }
  __syncthreads();
  int hl = t >> 7;
  float acc[BB];
#pragma unroll
  for (int b = 0; b < BB; ++b) acc[b] = 0.f;
  const float* wcol = qkv_w + (size_t)d0 * W3 + 2 * DIM + m;
#pragma unroll 4
  for (int dd = 0; dd < 32; ++dd) {
    float w = wcol[(size_t)dd * W3];
    const float4* u4 = reinterpret_cast<const float4*>(&us[hl][dd][0]);
    float4 u0 = u4[0], u1 = u4[1], u2 = u4[2], u3 = u4[3];  // broadcast
    acc[0]  += u0.x * w; acc[1]  += u0.y * w; acc[2]  += u0.z * w; acc[3]  += u0.w * w;
    acc[4]  += u1.x * w; acc[5]  += u1.y * w; acc[6]  += u1.z * w; acc[7]  += u1.w * w;
    acc[8]  += u2.x * w; acc[9]  += u2.y * w; acc[10] += u2.z * w; acc[11] += u2.w * w;
    acc[12] += u3.x * w; acc[13] += u3.y * w; acc[14] += u3.z * w; acc[15] += u3.w * w;
  }
  float bias = (dc == 0) ? qkv_b[2 * DIM + m] : 0.f;
#pragma unroll
  for (int b = 0; b < BB; ++b)
    atomicAdd(&ws[AO_OFF + b * DIM + m], acc[b] + bias);
}

// K7: out[b][n] += sum over 32-m chunk of ao[b][m]*proj_w[m][n] (+pb).
// ALL 16 batches per block -> proj_w read once. grid (8 nt, 64 mc).
__global__ __launch_bounds__(256) void k7_out(
    const float* __restrict__ proj_w, const float* __restrict__ proj_b,
    const float* __restrict__ ws, float* __restrict__ out) {
  int nt = blockIdx.x, mc = blockIdx.y, t = threadIdx.x;
  int n = nt * 256 + t;
  int m0 = mc * 32;
  __shared__ float as[32][20];
  for (int i = t; i < 32 * BB; i += 256) {
    int mm = i & 31, b = i >> 5;
    as[mm][b] = ws[AO_OFF + b * DIM + m0 + mm];
  }
  __syncthreads();
  float acc[BB];
#pragma unroll
  for (int b = 0; b < BB; ++b) acc[b] = 0.f;
  const float* wcol = proj_w + (size_t)m0 * DIM + n;
#pragma unroll 4
  for (int mm = 0; mm < 32; ++mm) {
    float w = wcol[(size_t)mm * DIM];
    const float4* a4 = reinterpret_cast<const float4*>(&as[mm][0]);
    float4 a0 = a4[0], a1 = a4[1], a2 = a4[2], a3 = a4[3];  // broadcast
    acc[0]  += a0.x * w; acc[1]  += a0.y * w; acc[2]  += a0.z * w; acc[3]  += a0.w * w;
    acc[4]  += a1.x * w; acc[5]  += a1.y * w; acc[6]  += a1.z * w; acc[7]  += a1.w * w;
    acc[8]  += a2.x * w; acc[9]  += a2.y * w; acc[10] += a2.z * w; acc[11] += a2.w * w;
    acc[12] += a3.x * w; acc[13] += a3.y * w; acc[14] += a3.z * w; acc[15] += a3.w * w;
  }
  float bias = (mc == 0) ? proj_b[n] : 0.f;
#pragma unroll
  for (int b = 0; b < BB; ++b)
    atomicAdd(&out[b * DIM + n], acc[b] + bias);
}

extern "C" void kernel_launch(void* const* d_in, const int* in_sizes, int n_in,
                              void* d_out, int out_size, void* d_ws, size_t ws_size,
                              hipStream_t stream) {
  const float* x      = (const float*)d_in[0];
  const float* pos    = (const float*)d_in[1];
  const float* cls    = (const float*)d_in[2];
  const float* qkv_w  = (const float*)d_in[3];
  const float* qkv_b  = (const float*)d_in[4];
  const float* proj_w = (const float*)d_in[5];
  const float* proj_b = (const float*)d_in[6];
  float* ws  = (float*)d_ws;
  float* out = (float*)d_out;

  // zero q, ao, r, gamma, scores, u (atomically accumulated) and d_out
  hipMemsetAsync(ws, 0, (size_t)RB_OFF * sizeof(float), stream);
  hipMemsetAsync(out, 0, (size_t)out_size * sizeof(float), stream);

  k1_q          <<<dim3(8, 64),     256, 0, stream>>>(pos, cls, qkv_w, qkv_b, ws);
  k2_r          <<<dim3(16, 16),    128, 0, stream>>>(qkv_w, ws);
  k2b_gamma     <<<16,              256, 0, stream>>>(pos, cls, ws);
  k3_scores_mfma<<<dim3(32, 16, 4),  64, 0, stream>>>(x, pos, ws);
  k4_softmax    <<<dim3(16, 16),    256, 0, stream>>>(ws);
  k5_u          <<<dim3(8, 8, 16),  256, 0, stream>>>(x, pos, cls, ws);
  k6_ao         <<<dim3(8, 64),     256, 0, stream>>>(qkv_w, qkv_b, ws);
  k7_out        <<<dim3(8, 64),     256, 0, stream>>>(proj_w, proj_b, ws, out);
}

// Round 6
// 222.070 us; speedup vs baseline: 1.1208x; 1.1208x over previous
//
#include <hip/hip_runtime.h>

// ViT cls-token-only forward. B=16, C=8, D=511, H=W=16, DIM=2048, SEQ=512,
// NH=16, HD=128.
// q = (cls+pos0) @ Wq + bq is batch-independent (one 2048-vector).
// scores[b,h,j] = tok[b,j] . r[h],  r[h] = Wk[:,h*128:+128] @ q[h]  (scaled)
// u[b,h] = sum_j p[b,h,j] * tok[b,j];  ao[b,h] = u[b,h] @ Wv slice + bv
// out[b] = ao[b] @ proj_w + proj_b
//
// R6: k5 (PV) -> MFMA. R5's scalar k5 was LDS-pipe-bound (256 broadcast
// ds_read_b128/wave vs 2k cyc FMA). Now u = p @ tok per batch via
// 16x16x32 bf16 MFMA, 3-term hi/lo compensation (same as k3): p staged in
// LDS (bf16 hi/lo, stride 520 shorts), tok converted on the fly, cls token
// folded into K-loop (j=0), plain coalesced store of u (no atomics).
// k2b fused into k2 (gamma via wave-reduce + atomicAdd). Memset covers only
// the atomic region (0.66 MB).

#define BB   16
#define CC   8
#define DD   511
#define DIM  2048
#define SEQ  512
#define NH   16
#define HD   128
#define W3   6144
#define SCALE 0.08838834764831845f

// workspace layout (float offsets)
#define Q_OFF   0            // 2048    atomic
#define AO_OFF  2048         // 32768   atomic
#define G_OFF   34816        // 16      atomic
#define SC_OFF  34832        // 131072  atomic (scores), softmax in place
#define ZERO_N  165904       // memset extent (floats)
#define R_OFF   165904       // 32768   fp32 r (plain write)
#define RB_OFF  198672       // 32768 float slots = 65536 shorts: r bf16 hi/lo
#define U_OFF   231440       // 524288  u (plain write by k5)
// total = 755,728 floats ~= 3.0 MB

typedef __attribute__((ext_vector_type(8))) short short8;
typedef __attribute__((ext_vector_type(4))) float floatx4;

static __device__ inline short bf_hi(float f) {
  return (short)(__float_as_uint(f) >> 16);          // truncate to bf16
}
static __device__ inline float bf_hif(float f) {
  return __uint_as_float(__float_as_uint(f) & 0xffff0000u);
}

// K1: q[n] = sum_d (cls[d]+pos[d]) * Wq[d][n] + bq[n]   grid (8 ntile, 64 dchunk)
__global__ __launch_bounds__(256) void k1_q(
    const float* __restrict__ pos, const float* __restrict__ cls,
    const float* __restrict__ qkv_w, const float* __restrict__ qkv_b,
    float* __restrict__ ws) {
  int n  = blockIdx.x * 256 + threadIdx.x;
  int d0 = blockIdx.y * 32;
  float acc = (blockIdx.y == 0) ? qkv_b[n] : 0.f;
#pragma unroll 8
  for (int d = d0; d < d0 + 32; ++d) {
    float t0 = cls[d] + pos[d];           // uniform -> scalar load
    acc += t0 * qkv_w[(size_t)d * W3 + n];
  }
  atomicAdd(&ws[Q_OFF + n], acc);
}

// K2: r[h][d] = SCALE * (Wk[d, h-slice] . q[h-slice]); writes fp32 r, bf16
// hi/lo, AND accumulates gamma[h] = tok0 . r[h] (k2b fused).
// grid (16 dtile, 16 h), block 128.
__global__ __launch_bounds__(128) void k2_r(
    const float* __restrict__ qkv_w, const float* __restrict__ pos,
    const float* __restrict__ cls, float* __restrict__ ws) {
  __shared__ float qs[HD];
  int h = blockIdx.y;
  int d = blockIdx.x * 128 + threadIdx.x;
  if (threadIdx.x < HD) qs[threadIdx.x] = ws[Q_OFF + h * HD + threadIdx.x];
  __syncthreads();
  const float4* w4 = reinterpret_cast<const float4*>(
      qkv_w + (size_t)d * W3 + DIM + h * HD);
  float acc = 0.f;
#pragma unroll 8
  for (int e4 = 0; e4 < 32; ++e4) {
    float4 w = w4[e4];
    acc += qs[e4*4+0]*w.x + qs[e4*4+1]*w.y + qs[e4*4+2]*w.z + qs[e4*4+3]*w.w;
  }
  float r = acc * SCALE;
  int i = h * DIM + d;
  ws[R_OFF + i] = r;
  short* rb = (short*)(ws + RB_OFF);
  rb[i] = bf_hi(r);
  rb[NH * DIM + i] = bf_hi(r - bf_hif(r));
  // fused gamma partial
  float g = (cls[d] + pos[d]) * r;
  for (int m = 1; m < 64; m <<= 1) g += __shfl_xor(g, m, 64);
  if ((threadIdx.x & 63) == 0) atomicAdd(&ws[G_OFF + h], g);
}

// K3: scores[b,h,j] for j>=1 via MFMA. Per-wave tile: 16 j x 16 h, K-quarter
// of 512. grid (32 jt, 16 b, 4 ks), block 64 (one wave).
// 3-term hi/lo compensation: hi*hi + hi*lo + lo*hi.
__global__ __launch_bounds__(64) void k3_scores_mfma(
    const float* __restrict__ x, const float* __restrict__ pos,
    float* __restrict__ ws) {
  int jt = blockIdx.x, b = blockIdx.y, ks = blockIdx.z;
  int l  = threadIdx.x;          // 0..63
  int m  = l & 15;               // A-row (j) / B-row (h)
  int kg = l >> 4;               // k-quad
  int jrow = 1 + jt * 16 + m;    // 1..512
  int jc = jrow < SEQ ? jrow : (SEQ - 1);   // clamp; jrow==512 masked at store
  const size_t xrow = (size_t)b * CC * DD * 256 + (size_t)(jc - 1) * 256;
  const short* rh = (const short*)(ws + RB_OFF);
  const short* rl = rh + NH * DIM;
  floatx4 acc = {0.f, 0.f, 0.f, 0.f};
#pragma unroll 2
  for (int kk = ks * 16; kk < ks * 16 + 16; ++kk) {
    int d0 = kk * 32 + kg * 8;            // 8 consecutive d for this lane
    int c = d0 >> 8, doff = d0 & 255;
    const float4* xp = reinterpret_cast<const float4*>(
        x + xrow + (size_t)c * DD * 256 + doff);
    const float4* pp = reinterpret_cast<const float4*>(
        pos + (size_t)jc * DIM + d0);
    float4 xa = xp[0], xb = xp[1];
    float4 pa = pp[0], pb = pp[1];
    float f[8] = {xa.x + pa.x, xa.y + pa.y, xa.z + pa.z, xa.w + pa.w,
                  xb.x + pb.x, xb.y + pb.y, xb.z + pb.z, xb.w + pb.w};
    short8 ahi, alo;
#pragma unroll
    for (int i = 0; i < 8; ++i) {
      ahi[i] = bf_hi(f[i]);
      alo[i] = bf_hi(f[i] - bf_hif(f[i]));   // f-hi exact, then truncate
    }
    short8 bhi = *reinterpret_cast<const short8*>(rh + m * DIM + d0);
    short8 blo = *reinterpret_cast<const short8*>(rl + m * DIM + d0);
    acc = __builtin_amdgcn_mfma_f32_16x16x32_bf16(ahi, bhi, acc, 0, 0, 0);
    acc = __builtin_amdgcn_mfma_f32_16x16x32_bf16(ahi, blo, acc, 0, 0, 0);
    acc = __builtin_amdgcn_mfma_f32_16x16x32_bf16(alo, bhi, acc, 0, 0, 0);
  }
  // C layout: col(h) = l&15, row(j) = (l>>4)*4 + reg  [m89-verified]
  int h = m;
#pragma unroll
  for (int reg = 0; reg < 4; ++reg) {
    int row = kg * 4 + reg;
    int j = 1 + jt * 16 + row;
    if (j < SEQ)
      atomicAdd(&ws[SC_OFF + (size_t)(b * NH + h) * SEQ + j], acc[reg]);
  }
}

// K4: softmax per (b,h) row of 512, in place. j=0 score comes from gamma[h].
__global__ __launch_bounds__(256) void k4_softmax(float* __restrict__ ws) {
  int h = blockIdx.x, b = blockIdx.y, t = threadIdx.x;
  float* sc = ws + SC_OFF + (size_t)(b * NH + h) * SEQ;
  __shared__ float red[256];
  float s0 = (t == 0) ? ws[G_OFF + h] : sc[t];
  float s1 = sc[t + 256];
  red[t] = fmaxf(s0, s1);
  __syncthreads();
  for (int s = 128; s > 0; s >>= 1) { if (t < s) red[t] = fmaxf(red[t], red[t + s]); __syncthreads(); }
  float m = red[0];
  __syncthreads();
  float e0 = __expf(s0 - m), e1 = __expf(s1 - m);
  red[t] = e0 + e1;
  __syncthreads();
  for (int s = 128; s > 0; s >>= 1) { if (t < s) red[t] += red[t + s]; __syncthreads(); }
  float inv = 1.f / red[0];
  sc[t] = e0 * inv;
  sc[t + 256] = e1 * inv;
}

// K5: u[b] (16h x 2048d) = p[b] (16x512) @ tok[b] (512x2048) via MFMA,
// 3-term hi/lo. p staged in LDS once per block (bf16 hi/lo, stride 520).
// cls token is j=0 inside the K-loop. Plain coalesced store, no atomics.
// grid (32 dt, 16 b), block 256 = 4 waves; wave w owns d-tile dt*64+w*16.
#define PSTR 520
__global__ __launch_bounds__(256) void k5_pv_mfma(
    const float* __restrict__ x, const float* __restrict__ pos,
    const float* __restrict__ cls, float* __restrict__ ws) {
  int dt = blockIdx.x, b = blockIdx.y, t = threadIdx.x;
  __shared__ short phl[NH * PSTR];
  __shared__ short pll[NH * PSTR];
  // stage p -> bf16 hi/lo in LDS
  const float* pb = ws + SC_OFF + (size_t)b * NH * SEQ;
  for (int i = t; i < NH * SEQ; i += 256) {
    int h = i >> 9, j = i & 511;
    float v = pb[h * SEQ + j];
    phl[h * PSTR + j] = bf_hi(v);
    pll[h * PSTR + j] = bf_hi(v - bf_hif(v));
  }
  __syncthreads();
  int w = t >> 6, l = t & 63;
  int m16 = l & 15, kq = l >> 4;
  int dcol = dt * 64 + w * 16 + m16;
  int c = dcol >> 8, doff = dcol & 255;
  const float* xcol = x + (size_t)b * CC * DD * 256 + (size_t)c * DD * 256 + doff;
  const float* pcol = pos + dcol;
  float clsv0 = cls[dcol];
  const short8* pph = reinterpret_cast<const short8*>(&phl[m16 * PSTR]);
  const short8* ppl = reinterpret_cast<const short8*>(&pll[m16 * PSTR]);
  floatx4 acc = {0.f, 0.f, 0.f, 0.f};
  for (int kk = 0; kk < 16; ++kk) {
    int jb = kk * 32 + kq * 8;
    // j = jb + e; tok[j][dcol] = (j==0 ? cls : x[j-1]) + pos[j]
    const float* xp = xcol + ((size_t)jb - 1) * 256;
    const float* xp_safe = (jb == 0) ? xcol : xp;   // keep load in-bounds
    float f[8];
    float x0 = xp_safe[0];
    f[0] = ((jb == 0) ? clsv0 : x0) + pcol[(size_t)jb * DIM];
#pragma unroll
    for (int e = 1; e < 8; ++e)
      f[e] = xp[(size_t)e * 256] + pcol[(size_t)(jb + e) * DIM];
    short8 thi, tlo;
#pragma unroll
    for (int i = 0; i < 8; ++i) {
      thi[i] = bf_hi(f[i]);
      tlo[i] = bf_hi(f[i] - bf_hif(f[i]));
    }
    short8 phi = pph[kk * 4 + kq];
    short8 plo = ppl[kk * 4 + kq];
    acc = __builtin_amdgcn_mfma_f32_16x16x32_bf16(phi, thi, acc, 0, 0, 0);
    acc = __builtin_amdgcn_mfma_f32_16x16x32_bf16(phi, tlo, acc, 0, 0, 0);
    acc = __builtin_amdgcn_mfma_f32_16x16x32_bf16(plo, thi, acc, 0, 0, 0);
  }
  // C: col(d) = l&15, row(h) = kq*4+reg
  float* ub = ws + U_OFF + (size_t)b * NH * DIM + dcol;
#pragma unroll
  for (int reg = 0; reg < 4; ++reg) {
    int h = kq * 4 + reg;
    ub[(size_t)h * DIM] = acc[reg];
  }
}

// K6: ao[b][m] += sum over 32-d chunk of u[b][h][d]*Wv[d][4096+m] (+bv),
// m = h*128+e. ALL 16 batches per block -> Wv read once. grid (8 nt, 64 dc).
__global__ __launch_bounds__(256) void k6_ao(
    const float* __restrict__ qkv_w, const float* __restrict__ qkv_b,
    float* __restrict__ ws) {
  int nt = blockIdx.x, dc = blockIdx.y, t = threadIdx.x;
  int m = nt * 256 + t;
  int h0 = nt * 2;                        // 2 heads per 256-wide n tile
  int d0 = dc * 32;
  __shared__ float us[2][32][20];         // stride 20: 16B-aligned rows
  for (int i = t; i < 2 * 32 * BB; i += 256) {
    int dd = i & 31, b = (i >> 5) & 15, hh = i >> 9;
    us[hh][dd][b] = ws[U_OFF + (size_t)(b * NH + h0 + hh) * DIM + d0 + dd];
  }
  __syncthreads();
  int hl = t >> 7;
  float acc[BB];
#pragma unroll
  for (int b = 0; b < BB; ++b) acc[b] = 0.f;
  const float* wcol = qkv_w + (size_t)d0 * W3 + 2 * DIM + m;
#pragma unroll 4
  for (int dd = 0; dd < 32; ++dd) {
    float w = wcol[(size_t)dd * W3];
    const float4* u4 = reinterpret_cast<const float4*>(&us[hl][dd][0]);
    float4 u0 = u4[0], u1 = u4[1], u2 = u4[2], u3 = u4[3];  // broadcast
    acc[0]  += u0.x * w; acc[1]  += u0.y * w; acc[2]  += u0.z * w; acc[3]  += u0.w * w;
    acc[4]  += u1.x * w; acc[5]  += u1.y * w; acc[6]  += u1.z * w; acc[7]  += u1.w * w;
    acc[8]  += u2.x * w; acc[9]  += u2.y * w; acc[10] += u2.z * w; acc[11] += u2.w * w;
    acc[12] += u3.x * w; acc[13] += u3.y * w; acc[14] += u3.z * w; acc[15] += u3.w * w;
  }
  float bias = (dc == 0) ? qkv_b[2 * DIM + m] : 0.f;
#pragma unroll
  for (int b = 0; b < BB; ++b)
    atomicAdd(&ws[AO_OFF + b * DIM + m], acc[b] + bias);
}

// K7: out[b][n] += sum over 32-m chunk of ao[b][m]*proj_w[m][n] (+pb).
// ALL 16 batches per block -> proj_w read once. grid (8 nt, 64 mc).
__global__ __launch_bounds__(256) void k7_out(
    const float* __restrict__ proj_w, const float* __restrict__ proj_b,
    const float* __restrict__ ws, float* __restrict__ out) {
  int nt = blockIdx.x, mc = blockIdx.y, t = threadIdx.x;
  int n = nt * 256 + t;
  int m0 = mc * 32;
  __shared__ float as[32][20];
  for (int i = t; i < 32 * BB; i += 256) {
    int mm = i & 31, b = i >> 5;
    as[mm][b] = ws[AO_OFF + b * DIM + m0 + mm];
  }
  __syncthreads();
  float acc[BB];
#pragma unroll
  for (int b = 0; b < BB; ++b) acc[b] = 0.f;
  const float* wcol = proj_w + (size_t)m0 * DIM + n;
#pragma unroll 4
  for (int mm = 0; mm < 32; ++mm) {
    float w = wcol[(size_t)mm * DIM];
    const float4* a4 = reinterpret_cast<const float4*>(&as[mm][0]);
    float4 a0 = a4[0], a1 = a4[1], a2 = a4[2], a3 = a4[3];  // broadcast
    acc[0]  += a0.x * w; acc[1]  += a0.y * w; acc[2]  += a0.z * w; acc[3]  += a0.w * w;
    acc[4]  += a1.x * w; acc[5]  += a1.y * w; acc[6]  += a1.z * w; acc[7]  += a1.w * w;
    acc[8]  += a2.x * w; acc[9]  += a2.y * w; acc[10] += a2.z * w; acc[11] += a2.w * w;
    acc[12] += a3.x * w; acc[13] += a3.y * w; acc[14] += a3.z * w; acc[15] += a3.w * w;
  }
  float bias = (mc == 0) ? proj_b[n] : 0.f;
#pragma unroll
  for (int b = 0; b < BB; ++b)
    atomicAdd(&out[b * DIM + n], acc[b] + bias);
}

extern "C" void kernel_launch(void* const* d_in, const int* in_sizes, int n_in,
                              void* d_out, int out_size, void* d_ws, size_t ws_size,
                              hipStream_t stream) {
  const float* x      = (const float*)d_in[0];
  const float* pos    = (const float*)d_in[1];
  const float* cls    = (const float*)d_in[2];
  const float* qkv_w  = (const float*)d_in[3];
  const float* qkv_b  = (const float*)d_in[4];
  const float* proj_w = (const float*)d_in[5];
  const float* proj_b = (const float*)d_in[6];
  float* ws  = (float*)d_ws;
  float* out = (float*)d_out;

  // zero only the atomic accumulators (q, ao, gamma, scores) and d_out
  hipMemsetAsync(ws, 0, (size_t)ZERO_N * sizeof(float), stream);
  hipMemsetAsync(out, 0, (size_t)out_size * sizeof(float), stream);

  k1_q          <<<dim3(8, 64),     256, 0, stream>>>(pos, cls, qkv_w, qkv_b, ws);
  k2_r          <<<dim3(16, 16),    128, 0, stream>>>(qkv_w, pos, cls, ws);
  k3_scores_mfma<<<dim3(32, 16, 4),  64, 0, stream>>>(x, pos, ws);
  k4_softmax    <<<dim3(16, 16),    256, 0, stream>>>(ws);
  k5_pv_mfma    <<<dim3(32, 16),    256, 0, stream>>>(x, pos, cls, ws);
  k6_ao         <<<dim3(8, 64),     256, 0, stream>>>(qkv_w, qkv_b, ws);
  k7_out        <<<dim3(8, 64),     256, 0, stream>>>(proj_w, proj_b, ws, out);
}